// Round 8
// baseline (456.253 us; speedup 1.0000x reference)
//
#include <hip/hip_runtime.h>

#define B_ 4
#define L_ 1024
#define H_ 32
#define HKV_ 8
#define DH_ 128
#define SCALE_ 0.08838834764831845f
#define M_FIX 20.0f
#define KEEP_ 512
#define O_ELEMS (B_*L_*H_*DH_)          // 16777216
#define CACHE_ELEMS (8192*HKV_*DH_)     // 8388608
#define TILE_US 8192                    // 64*128 bf16 elems per staged tile
#define QTAB_US 2097152                 // 256 blocks * 4 c * 256 t * 8 shorts = 4 MB

typedef short short8 __attribute__((ext_vector_type(8)));
typedef float floatx4 __attribute__((ext_vector_type(4)));
typedef unsigned int uintx2 __attribute__((ext_vector_type(2)));
typedef unsigned int uintx4 __attribute__((ext_vector_type(4)));

__device__ inline unsigned short bf16r(float x) {
    unsigned int u = __builtin_bit_cast(unsigned int, x);
    u += 0x7fffu + ((u >> 16) & 1u);
    return (unsigned short)(u >> 16);
}
__device__ inline unsigned int pk_bf16(float a, float b) {
    return (unsigned int)bf16r(a) | ((unsigned int)bf16r(b) << 16);
}
__device__ inline float bf16tof(unsigned short h) {
    unsigned int u = ((unsigned int)h) << 16;
    return __builtin_bit_cast(float, u);
}

// ---------------- pre-pass: fp32 K/V -> bf16 tiles in LDS-ready swizzled layout ----------------
// grid 512 = b*128 + hkv*16 + kt. Tile base = bid*8192.
// Blocks with bid<256 additionally produce the sample-Q split-bf16 tables.
__global__ __launch_bounds__(256)
void convert_kernel(const float* __restrict__ Kp, const float* __restrict__ Vp,
                    const float* __restrict__ Qp,
                    unsigned short* __restrict__ Kb, unsigned short* __restrict__ Klo,
                    unsigned short* __restrict__ VTb,
                    unsigned short* __restrict__ Qh, unsigned short* __restrict__ Ql)
{
    int bid = blockIdx.x;
    int kt = bid & 15, hkv = (bid >> 4) & 7, b = bid >> 7;
    int t = threadIdx.x;
    size_t tile = (size_t)bid * TILE_US;

    // ---- K: hi + lo split (hi buffer doubles as attn's bf16 K) ----
    #pragma unroll
    for (int i = 0; i < 4; ++i) {
        int pos = t + 256 * i;
        int col = pos >> 4, gd = pos & 15;
        const float* kb = &Kp[((size_t)(b * L_ + kt * 64 + col) * HKV_ + hkv) * DH_ + gd * 8];
        float x[8];
        *(float4*)&x[0] = *(const float4*)kb;
        *(float4*)&x[4] = *(const float4*)(kb + 4);
        unsigned int gh[4], gl[4];
        #pragma unroll
        for (int j = 0; j < 4; ++j) {
            unsigned short h0 = bf16r(x[2*j]),   h1 = bf16r(x[2*j+1]);
            unsigned short l0 = bf16r(x[2*j]   - bf16tof(h0));
            unsigned short l1 = bf16r(x[2*j+1] - bf16tof(h1));
            gh[j] = (unsigned int)h0 | ((unsigned int)h1 << 16);
            gl[j] = (unsigned int)l0 | ((unsigned int)l1 << 16);
        }
        int phys = gd ^ (col & 15);
        *(uintx4*)&Kb[tile + col * 128 + phys * 8]  = (uintx4){gh[0], gh[1], gh[2], gh[3]};
        *(uintx4*)&Klo[tile + col * 128 + phys * 8] = (uintx4){gl[0], gl[1], gl[2], gl[3]};
    }

    // ---- V^T ----
    {
        int d4g = t & 31, g = t >> 5;    // g = k-granule (8 rows)
        const float* vb = &Vp[((size_t)(b * L_ + kt * 64 + g * 8) * HKV_ + hkv) * DH_ + d4g * 4];
        const size_t vs = (size_t)HKV_ * DH_;
        float4 r[8];
        #pragma unroll
        for (int j = 0; j < 8; ++j) r[j] = *(const float4*)(vb + (size_t)j * vs);
        #pragma unroll
        for (int ii = 0; ii < 4; ++ii) {
            int d = d4g * 4 + ii;
            int phys = g ^ (d & 7);
            uintx4 gp;
            gp[0] = pk_bf16(((const float*)&r[0])[ii], ((const float*)&r[1])[ii]);
            gp[1] = pk_bf16(((const float*)&r[2])[ii], ((const float*)&r[3])[ii]);
            gp[2] = pk_bf16(((const float*)&r[4])[ii], ((const float*)&r[5])[ii]);
            gp[3] = pk_bf16(((const float*)&r[6])[ii], ((const float*)&r[7])[ii]);
            *(uintx4*)&VTb[tile + d * 64 + phys * 8] = gp;
        }
    }

    // ---- sample-Q split frags (first 256 blocks) ----
    if (bid < 256) {
        int qts = bid & 1;
        int h   = (bid >> 1) & 31;
        int qb_ = bid >> 6;
        int w = t >> 6, l = t & 63, lm = l & 15, hq = l >> 4;
        int q0 = 896 + qts * 64;
        const float* qb = Qp + ((size_t)(qb_ * L_ + q0 + w * 16 + lm) * H_ + h) * DH_;
        #pragma unroll
        for (int c = 0; c < 4; ++c) {
            int dc = hq * 8 + 32 * c;
            float x[8];
            *(float4*)&x[0] = *(const float4*)(qb + dc);
            *(float4*)&x[4] = *(const float4*)(qb + dc + 4);
            short8 fh, fl;
            #pragma unroll
            for (int j = 0; j < 8; ++j) {
                float xs = x[j] * SCALE_;
                unsigned short hb = bf16r(xs);
                fh[j] = (short)hb;
                fl[j] = (short)bf16r(xs - bf16tof(hb));
            }
            size_t idx = (((size_t)bid * 4 + c) * 256 + t) * 8;
            *(short8*)&Qh[idx] = fh;
            *(short8*)&Ql[idx] = fl;
        }
    }
}

// ---------------- full causal attention, fixed-M bf16 MFMA flash ----------------
// grid 1024 = (b,h,pr); 4 waves; phases qt=pr and qt=15-pr (uniform 17 tiles).
// LDS 40960 B -> 4 blocks/CU (LDS-capped). waves_per_eu(4,4) clamps occupancy
// to that, giving the allocator a 128-VGPR budget so the T14 register prefetch
// (kpre/vpre, +32 VGPR) does NOT spill (round-5 failure mode).
__attribute__((amdgpu_waves_per_eu(4, 4)))
__global__ __launch_bounds__(256)
void attn_mfma(const float* __restrict__ Qp, const unsigned short* __restrict__ Kbp,
               const unsigned short* __restrict__ VTp, float* __restrict__ Op)
{
    __shared__ __align__(16) unsigned short k_lds[64 * 128];   // [col][d], 16B-granule XOR swizzle by col&15
    __shared__ __align__(16) unsigned short vT[128 * 64];      // [d][k],  granule XOR swizzle by d&7
    __shared__ __align__(16) unsigned short p_lds[4 * 1024];   // per-wave [m][k], granule XOR by m&7

    int bid = blockIdx.x;
    int pr = bid & 7;
    int h  = (bid >> 3) & 31;
    int b  = bid >> 8;
    int hkv = h >> 2;
    int t = threadIdx.x;
    int w = t >> 6;
    int l = t & 63;
    int lm = l & 15;
    int hq = l >> 4;

    for (int ph = 0; ph < 2; ++ph) {
        int qt = ph ? (15 - pr) : pr;

        // Q A-frags (scale folded): A[m=lm][k=hq*8+j+32kc]
        short8 aq[4];
        {
            const float* qb = Qp + ((size_t)(b * L_ + qt * 64 + w * 16 + lm) * H_ + h) * DH_;
            #pragma unroll
            for (int c = 0; c < 4; ++c) {
                int dc = hq * 8 + 32 * c;
                float4 x0 = *(const float4*)(qb + dc);
                float4 x1 = *(const float4*)(qb + dc + 4);
                uintx4 packed;
                packed[0] = pk_bf16(x0.x * SCALE_, x0.y * SCALE_);
                packed[1] = pk_bf16(x0.z * SCALE_, x0.w * SCALE_);
                packed[2] = pk_bf16(x1.x * SCALE_, x1.y * SCALE_);
                packed[3] = pk_bf16(x1.z * SCALE_, x1.w * SCALE_);
                aq[c] = __builtin_bit_cast(short8, packed);
            }
        }

        // prologue: prefetch tile kt=0 into registers
        uintx4 kpre[4], vpre[4];
        {
            size_t tb0 = (size_t)((b * HKV_ + hkv) * 16 + 0) * TILE_US;
            const uintx4* kg = (const uintx4*)(Kbp + tb0) + t;
            const uintx4* vg = (const uintx4*)(VTp + tb0) + t;
            #pragma unroll
            for (int i = 0; i < 4; ++i) { kpre[i] = kg[i * 256]; vpre[i] = vg[i * 256]; }
        }

        floatx4 O[8];
        #pragma unroll
        for (int n = 0; n < 8; ++n) O[n] = (floatx4){0.f, 0.f, 0.f, 0.f};
        float l_acc[4] = {0.f, 0.f, 0.f, 0.f};

        for (int kt = 0; kt <= qt; ++kt) {
            __syncthreads();    // prior iteration's LDS reads complete
            {
                uintx4* kd = (uintx4*)k_lds + t;
                uintx4* vd = (uintx4*)vT + t;
                #pragma unroll
                for (int i = 0; i < 4; ++i) { kd[i * 256] = kpre[i]; vd[i * 256] = vpre[i]; }
            }
            __syncthreads();    // staging visible
            // issue next tile's global loads; latency hides under compute below
            if (kt < qt) {
                size_t tb = (size_t)((b * HKV_ + hkv) * 16 + kt + 1) * TILE_US;
                const uintx4* kg = (const uintx4*)(Kbp + tb) + t;
                const uintx4* vg = (const uintx4*)(VTp + tb) + t;
                #pragma unroll
                for (int i = 0; i < 4; ++i) { kpre[i] = kg[i * 256]; vpre[i] = vg[i * 256]; }
            }

            // QK^T: S[c] col n=lm <-> k_phys = lm*4+c ; C-init = -M (fixed-M softmax)
            floatx4 S[4];
            #pragma unroll
            for (int c = 0; c < 4; ++c) S[c] = (floatx4){-M_FIX, -M_FIX, -M_FIX, -M_FIX};
            #pragma unroll
            for (int kc = 0; kc < 4; ++kc) {
                #pragma unroll
                for (int c = 0; c < 4; ++c) {
                    int row = lm * 4 + c;
                    int phys = (kc * 4 + hq) ^ (row & 15);
                    short8 bk = *(const short8*)&k_lds[row * 128 + phys * 8];
                    S[c] = __builtin_amdgcn_mfma_f32_16x16x32_bf16(aq[kc], bk, S[c], 0, 0, 0);
                }
            }
            bool diag = (kt == qt);
            #pragma unroll
            for (int r = 0; r < 4; ++r) {
                float e0 = __expf(S[0][r]);
                float e1 = __expf(S[1][r]);
                float e2 = __expf(S[2][r]);
                float e3 = __expf(S[3][r]);
                if (diag) {
                    int qabs = qt * 64 + w * 16 + hq * 4 + r;
                    int kb0 = kt * 64 + lm * 4;
                    e0 = (kb0 + 0 <= qabs) ? e0 : 0.f;
                    e1 = (kb0 + 1 <= qabs) ? e1 : 0.f;
                    e2 = (kb0 + 2 <= qabs) ? e2 : 0.f;
                    e3 = (kb0 + 3 <= qabs) ? e3 : 0.f;
                }
                l_acc[r] += (e0 + e1) + (e2 + e3);
                int m = hq * 4 + r;
                int phys = (lm >> 1) ^ (m & 7);
                uintx2 gp;
                gp[0] = pk_bf16(e0, e1);
                gp[1] = pk_bf16(e2, e3);
                *(uintx2*)&p_lds[w * 1024 + m * 64 + phys * 8 + (lm & 1) * 4] = gp;
            }
            asm volatile("" ::: "memory");
            // PV as O^T = V^T * P^T  (A = V^T frag, B = P^T frag)
            int phys0 = hq ^ (lm & 7);
            int phys1 = (4 + hq) ^ (lm & 7);
            short8 bp0 = *(const short8*)&p_lds[w * 1024 + lm * 64 + phys0 * 8];
            short8 bp1 = *(const short8*)&p_lds[w * 1024 + lm * 64 + phys1 * 8];
            #pragma unroll
            for (int n = 0; n < 8; ++n) {
                int d = n * 16 + lm;
                short8 a0 = *(const short8*)&vT[d * 64 + (hq ^ (d & 7)) * 8];
                O[n] = __builtin_amdgcn_mfma_f32_16x16x32_bf16(a0, bp0, O[n], 0, 0, 0);
                short8 a1 = *(const short8*)&vT[d * 64 + (((4 + hq) ^ (d & 7))) * 8];
                O[n] = __builtin_amdgcn_mfma_f32_16x16x32_bf16(a1, bp1, O[n], 0, 0, 0);
            }
        }
        // one-time l reduce + broadcast via p_lds (own-wave region)
        #pragma unroll
        for (int r = 0; r < 4; ++r) {
            l_acc[r] += __shfl_xor(l_acc[r], 1);
            l_acc[r] += __shfl_xor(l_acc[r], 2);
            l_acc[r] += __shfl_xor(l_acc[r], 4);
            l_acc[r] += __shfl_xor(l_acc[r], 8);
        }
        float* lf = (float*)&p_lds[w * 1024];
        if (lm == 0) {
            #pragma unroll
            for (int r = 0; r < 4; ++r) lf[hq * 4 + r] = l_acc[r];
        }
        asm volatile("" ::: "memory");
        __builtin_amdgcn_wave_barrier();
        float invl = 1.0f / lf[lm];
        // O^T epilogue: lane owns q = w*16+lm, d = n*16+hq*4..+3 -> float4 stores
        #pragma unroll
        for (int n = 0; n < 8; ++n) {
            float4 res;
            res.x = O[n][0] * invl; res.y = O[n][1] * invl;
            res.z = O[n][2] * invl; res.w = O[n][3] * invl;
            *(float4*)&Op[((size_t)(b * L_ + qt * 64 + w * 16 + lm) * H_ + h) * DH_ + n * 16 + hq * 4] = res;
        }
    }
}

// ---------------- importance A: chunked partial row-sums (4x parallelism of old imp_l) --------
// grid 1024 = (b,h,qts,chunk). Block processes tiles kt in [chunk*4, min(chunk*4+3, ktd)],
// writes per-chunk partial sums lpart[(qblock*64 + row)*4 + chunk]. Deterministic combine
// happens in imp_col (fixed order), so no atomics and no init needed (every slot written).
__global__ __launch_bounds__(256)
void imp_lsum_kernel(const unsigned short* __restrict__ Qhp, const unsigned short* __restrict__ Qlp,
                     const unsigned short* __restrict__ Kbp, const unsigned short* __restrict__ Klop,
                     float* __restrict__ lpart)
{
    __shared__ __align__(16) unsigned short khi[64 * 128];
    __shared__ __align__(16) unsigned short klo[64 * 128];

    int bid = blockIdx.x;
    int chunk = bid & 3;
    int qts = (bid >> 2) & 1;
    int h   = (bid >> 3) & 31;
    int b   = bid >> 8;
    int hkv = h >> 2;
    int qblock = (b * 32 + h) * 2 + qts;
    int t = threadIdx.x;
    int w = t >> 6;
    int l = t & 63;
    int lm = l & 15;
    int hq = l >> 4;
    int q0 = 896 + qts * 64;
    int ktd = q0 >> 6;
    int kt_lo = chunk * 4;
    int kt_hi = min(kt_lo + 3, ktd);

    short8 aqh[4], aql[4];
    #pragma unroll
    for (int c = 0; c < 4; ++c) {
        size_t idx = (((size_t)qblock * 4 + c) * 256 + t) * 8;
        aqh[c] = *(const short8*)&Qhp[idx];
        aql[c] = *(const short8*)&Qlp[idx];
    }

    float l_acc[4] = {0.f, 0.f, 0.f, 0.f};
    for (int kt = kt_lo; kt <= kt_hi; ++kt) {
        __syncthreads();
        size_t tbase = (size_t)((b * HKV_ + hkv) * 16 + kt) * TILE_US;
        {
            const uintx4* hg = (const uintx4*)(Kbp + tbase) + t;
            const uintx4* lg = (const uintx4*)(Klop + tbase) + t;
            uintx4* hd = (uintx4*)khi + t;
            uintx4* ld = (uintx4*)klo + t;
            #pragma unroll
            for (int i = 0; i < 4; ++i) {
                hd[i * 256] = hg[i * 256];
                ld[i * 256] = lg[i * 256];
            }
        }
        __syncthreads();

        floatx4 S[4];
        #pragma unroll
        for (int c = 0; c < 4; ++c) S[c] = (floatx4){-M_FIX, -M_FIX, -M_FIX, -M_FIX};
        #pragma unroll
        for (int kc = 0; kc < 4; ++kc) {
            #pragma unroll
            for (int c = 0; c < 4; ++c) {
                int row = lm * 4 + c;
                int phys = (kc * 4 + hq) ^ (row & 15);
                short8 bh = *(const short8*)&khi[row * 128 + phys * 8];
                short8 bl = *(const short8*)&klo[row * 128 + phys * 8];
                S[c] = __builtin_amdgcn_mfma_f32_16x16x32_bf16(aqh[kc], bh, S[c], 0, 0, 0);
                S[c] = __builtin_amdgcn_mfma_f32_16x16x32_bf16(aqh[kc], bl, S[c], 0, 0, 0);
                S[c] = __builtin_amdgcn_mfma_f32_16x16x32_bf16(aql[kc], bh, S[c], 0, 0, 0);
            }
        }
        bool diag = (kt == ktd);
        #pragma unroll
        for (int r = 0; r < 4; ++r) {
            int qabs = q0 + w * 16 + hq * 4 + r;
            #pragma unroll
            for (int c = 0; c < 4; ++c) {
                float ev = __expf(S[c][r]);
                if (diag) {
                    int kabs = kt * 64 + lm * 4 + c;
                    ev = (kabs <= qabs) ? ev : 0.f;
                }
                l_acc[r] += ev;
            }
        }
    }
    #pragma unroll
    for (int r = 0; r < 4; ++r) {
        l_acc[r] += __shfl_xor(l_acc[r], 1);
        l_acc[r] += __shfl_xor(l_acc[r], 2);
        l_acc[r] += __shfl_xor(l_acc[r], 4);
        l_acc[r] += __shfl_xor(l_acc[r], 8);
    }
    if (lm == 0) {
        #pragma unroll
        for (int r = 0; r < 4; ++r) {
            int row = w * 16 + hq * 4 + r;
            lpart[((size_t)qblock * 64 + row) * 4 + chunk] = l_acc[r];
        }
    }
}

// ---------------- importance B: column sums per (b,h,kt) ----------------
// grid 2048 = (b,h,kt); combines lpart chunks in fixed order -> deterministic 1/l.
__global__ __launch_bounds__(256, 4)
void imp_col_kernel(const unsigned short* __restrict__ Qhp, const unsigned short* __restrict__ Qlp,
                    const unsigned short* __restrict__ Kbp, const unsigned short* __restrict__ Klop,
                    const float* __restrict__ lpart, float* __restrict__ imp)
{
    __shared__ __align__(16) unsigned short khi[64 * 128];
    __shared__ __align__(16) unsigned short klo[64 * 128];
    __shared__ float imp_loc[64];

    int bid = blockIdx.x;
    int kt = bid & 15;
    int h  = (bid >> 4) & 31;
    int b  = bid >> 9;
    int hkv = h >> 2;
    int t = threadIdx.x;
    int w = t >> 6;
    int l = t & 63;
    int lm = l & 15;
    int hq = l >> 4;

    if (t < 64) imp_loc[t] = 0.f;
    size_t tbase = (size_t)((b * HKV_ + hkv) * 16 + kt) * TILE_US;
    {
        const uintx4* hg = (const uintx4*)(Kbp + tbase) + t;
        const uintx4* lg = (const uintx4*)(Klop + tbase) + t;
        uintx4* hd = (uintx4*)khi + t;
        uintx4* ld = (uintx4*)klo + t;
        #pragma unroll
        for (int i = 0; i < 4; ++i) {
            hd[i * 256] = hg[i * 256];
            ld[i * 256] = lg[i * 256];
        }
    }
    __syncthreads();

    float cs[4] = {0.f, 0.f, 0.f, 0.f};
    for (int qp2 = 0; qp2 < 2; ++qp2) {
        if (kt == 15 && qp2 == 0) continue;
        int qbid = (b * 32 + h) * 2 + qp2;
        int q0 = 896 + qp2 * 64;
        short8 aqh[4], aql[4];
        #pragma unroll
        for (int c = 0; c < 4; ++c) {
            size_t idx = (((size_t)qbid * 4 + c) * 256 + t) * 8;
            aqh[c] = *(const short8*)&Qhp[idx];
            aql[c] = *(const short8*)&Qlp[idx];
        }
        floatx4 iv4;
        #pragma unroll
        for (int r = 0; r < 4; ++r) {
            int row = w * 16 + hq * 4 + r;
            float4 p = *(const float4*)&lpart[((size_t)qbid * 64 + row) * 4];
            iv4[r] = 1.0f / ((p.x + p.y) + (p.z + p.w));
        }

        floatx4 S[4];
        #pragma unroll
        for (int c = 0; c < 4; ++c) S[c] = (floatx4){-M_FIX, -M_FIX, -M_FIX, -M_FIX};
        #pragma unroll
        for (int kc = 0; kc < 4; ++kc) {
            #pragma unroll
            for (int c = 0; c < 4; ++c) {
                int row = lm * 4 + c;
                int phys = (kc * 4 + hq) ^ (row & 15);
                short8 bh = *(const short8*)&khi[row * 128 + phys * 8];
                short8 bl = *(const short8*)&klo[row * 128 + phys * 8];
                S[c] = __builtin_amdgcn_mfma_f32_16x16x32_bf16(aqh[kc], bh, S[c], 0, 0, 0);
                S[c] = __builtin_amdgcn_mfma_f32_16x16x32_bf16(aqh[kc], bl, S[c], 0, 0, 0);
                S[c] = __builtin_amdgcn_mfma_f32_16x16x32_bf16(aql[kc], bh, S[c], 0, 0, 0);
            }
        }
        #pragma unroll
        for (int c = 0; c < 4; ++c) {
            int kabs = kt * 64 + lm * 4 + c;
            #pragma unroll
            for (int r = 0; r < 4; ++r) {
                int qabs = q0 + w * 16 + hq * 4 + r;
                float ev = (kabs <= qabs) ? __expf(S[c][r]) : 0.f;
                cs[c] += ev * iv4[r];
            }
        }
    }
    #pragma unroll
    for (int c = 0; c < 4; ++c) {
        cs[c] += __shfl_xor(cs[c], 16);
        cs[c] += __shfl_xor(cs[c], 32);
    }
    if (l < 16) {
        #pragma unroll
        for (int c = 0; c < 4; ++c) atomicAdd(&imp_loc[lm * 4 + c], cs[c]);
    }
    __syncthreads();
    if (t < 64) atomicAdd(&imp[b * L_ + kt * 64 + t], imp_loc[t]);
}

// ---------------- top-k 512 of 1024 per batch; optionally emits inverse slot map ----------------
__global__ void topk_kernel(const float* __restrict__ imp, const int* __restrict__ slot_mapping,
                            int* __restrict__ keep, int* __restrict__ inv)
{
    __shared__ float vals[1024];
    __shared__ int   idxs[1024];
    int b = blockIdx.x;
    int t = threadIdx.x;   // 512 threads
    for (int i = t; i < 1024; i += 512) { vals[i] = imp[b * L_ + i]; idxs[i] = i; }

    for (int size = 2; size <= 1024; size <<= 1) {
        for (int stride = size >> 1; stride > 0; stride >>= 1) {
            __syncthreads();
            for (int i = t; i < 1024; i += 512) {
                int j = i ^ stride;
                if (j > i) {
                    float vi = vals[i], vj = vals[j];
                    int ii = idxs[i], ij = idxs[j];
                    bool j_before_i = (vj > vi) || (vj == vi && ij < ii);
                    bool descRegion = ((i & size) == 0);
                    bool doSwap = descRegion ? j_before_i : !j_before_i;
                    if (doSwap) {
                        vals[i] = vj; vals[j] = vi;
                        idxs[i] = ij; idxs[j] = ii;
                    }
                }
            }
        }
    }
    __syncthreads();
    for (int size = 2; size <= 512; size <<= 1) {
        for (int stride = size >> 1; stride > 0; stride >>= 1) {
            __syncthreads();
            int i = t, j = t ^ stride;
            if (j > i) {
                int a = idxs[i], bb = idxs[j];
                bool ascRegion = ((i & size) == 0);
                bool doSwap = ascRegion ? (a > bb) : (a < bb);
                if (doSwap) { idxs[i] = bb; idxs[j] = a; }
            }
        }
    }
    __syncthreads();
    keep[b * KEEP_ + t] = idxs[t];
    if (inv) {
        int dest = slot_mapping[b * L_ + t];        // j = t < 512
        inv[dest] = b * L_ + idxs[t];               // global source row
    }
}

// ---------------- fused cache output: every slot written exactly once ----------------
__global__ __launch_bounds__(256)
void cache_out_kernel(const float* __restrict__ kin, const float* __restrict__ vin,
                      const float* __restrict__ kc_in, const float* __restrict__ vc_in,
                      const int* __restrict__ inv,
                      float* __restrict__ kc_out, float* __restrict__ vc_out)
{
    int bid = blockIdx.x;
    int t = threadIdx.x;
    #pragma unroll
    for (int i = 0; i < 4; ++i) {
        int s = bid * 4 + i;
        int src = inv[s];
        const float4* kp = (src >= 0) ? (const float4*)&kin[(size_t)src * 1024]
                                      : (const float4*)&kc_in[(size_t)s * 1024];
        const float4* vp = (src >= 0) ? (const float4*)&vin[(size_t)src * 1024]
                                      : (const float4*)&vc_in[(size_t)s * 1024];
        ((float4*)&kc_out[(size_t)s * 1024])[t] = kp[t];
        ((float4*)&vc_out[(size_t)s * 1024])[t] = vp[t];
    }
}

// ---------------- fallback pair (used only if workspace too small for inv) ----------------
__global__ __launch_bounds__(256)
void cache_copy_kernel(const float* __restrict__ kc_in, const float* __restrict__ vc_in,
                       float* __restrict__ kc_out, float* __restrict__ vc_out)
{
    size_t idx = (size_t)blockIdx.x * 256 + threadIdx.x;
    const float4* ki = (const float4*)kc_in;
    const float4* vi = (const float4*)vc_in;
    float4* ko = (float4*)kc_out;
    float4* vo = (float4*)vc_out;
    #pragma unroll
    for (int i = 0; i < 4; ++i) {
        size_t off = idx + (size_t)i * 524288;
        ko[off] = ki[off];
        vo[off] = vi[off];
    }
}

__global__ void scatter_kernel(const float* __restrict__ kin, const float* __restrict__ vin,
                               const int* __restrict__ keep, const int* __restrict__ slot_mapping,
                               float* __restrict__ kc_out, float* __restrict__ vc_out)
{
    int bid = blockIdx.x;
    int b = bid >> 9, j = bid & 511;
    int src = b * L_ + keep[b * KEEP_ + j];
    int dst = slot_mapping[b * L_ + j];
    int t = threadIdx.x;
    float4 kv = *(const float4*)&kin[(size_t)src * 1024 + t * 4];
    *(float4*)&kc_out[(size_t)dst * 1024 + t * 4] = kv;
    float4 vv = *(const float4*)&vin[(size_t)src * 1024 + t * 4];
    *(float4*)&vc_out[(size_t)dst * 1024 + t * 4] = vv;
}

extern "C" void kernel_launch(void* const* d_in, const int* in_sizes, int n_in,
                              void* d_out, int out_size, void* d_ws, size_t ws_size,
                              hipStream_t stream)
{
    const float* q = (const float*)d_in[0];
    const float* k = (const float*)d_in[1];
    const float* v = (const float*)d_in[2];
    const float* k_cache = (const float*)d_in[3];
    const float* v_cache = (const float*)d_in[4];
    const int* slot_mapping = (const int*)d_in[5];

    float* o = (float*)d_out;
    float* kc_out = o + O_ELEMS;
    float* vc_out = kc_out + CACHE_ELEMS;

    // workspace: imp 16K | keep 8K | (unused 64K) | inv 32K  (120 KB)
    float* imp  = (float*)d_ws;                    // 4096 f
    int*   keep = (int*)(imp + B_ * L_);           // 2048 i
    float* invL = (float*)(keep + B_ * KEEP_);     // 16384 f (layout-compat spacer)
    int*   inv  = (int*)(invL + B_ * H_ * 128);    // 8192 i @ 88 KB
    bool use_inv = ws_size >= (size_t)(120 * 1024);
    if (!use_inv) inv = nullptr;

    // lpart (256 KB partial row-sums) lives in the kc_out output region, which is
    // untouched until cache-out time (after all lpart consumers).
    float* lpart = kc_out;

    // bf16 staging scratch (32 MB): Kb/Klo/VTb 8MB each + Qh/Ql 4MB each.
    const size_t SCRATCH_US = (size_t)3 * 512 * TILE_US + (size_t)2 * QTAB_US;
    bool ws_fits = ws_size >= (size_t)(128 * 1024) + SCRATCH_US * sizeof(unsigned short);
    unsigned short* Kb = ws_fits ? (unsigned short*)((char*)d_ws + 128 * 1024)
                                 : (unsigned short*)vc_out;
    unsigned short* Klo = Kb  + (size_t)512 * TILE_US;
    unsigned short* VTb = Klo + (size_t)512 * TILE_US;
    unsigned short* Qh  = VTb + (size_t)512 * TILE_US;
    unsigned short* Ql  = Qh  + (size_t)QTAB_US;

    (void)hipMemsetAsync(imp, 0, B_ * L_ * 4, stream);
    if (use_inv) (void)hipMemsetAsync(inv, 0xFF, 8192 * 4, stream);   // -1 sentinel

    convert_kernel<<<dim3(512), dim3(256), 0, stream>>>(k, v, q, Kb, Klo, VTb, Qh, Ql);
    attn_mfma<<<dim3(1024), dim3(256), 0, stream>>>(q, Kb, VTb, o);
    imp_lsum_kernel<<<dim3(1024), dim3(256), 0, stream>>>(Qh, Ql, Kb, Klo, lpart);
    imp_col_kernel<<<dim3(2048), dim3(256), 0, stream>>>(Qh, Ql, Kb, Klo, lpart, imp);
    topk_kernel<<<dim3(4), dim3(512), 0, stream>>>(imp, slot_mapping, keep, inv);

    if (use_inv) {
        cache_out_kernel<<<dim3(2048), dim3(256), 0, stream>>>(k, v, k_cache, v_cache, inv, kc_out, vc_out);
    } else {
        cache_copy_kernel<<<dim3(2048), dim3(256), 0, stream>>>(k_cache, v_cache, kc_out, vc_out);
        scatter_kernel<<<dim3(2048), dim3(256), 0, stream>>>(k, v, keep, slot_mapping, kc_out, vc_out);
    }
}

// Round 9
// 395.806 us; speedup vs baseline: 1.1527x; 1.1527x over previous
//
#include <hip/hip_runtime.h>

#define B_ 4
#define L_ 1024
#define H_ 32
#define HKV_ 8
#define DH_ 128
#define SCALE_ 0.08838834764831845f
#define M_FIX 20.0f
#define KEEP_ 512
#define O_ELEMS (B_*L_*H_*DH_)          // 16777216
#define CACHE_ELEMS (8192*HKV_*DH_)     // 8388608
#define TILE_US 8192                    // 64*128 bf16 elems per staged tile
#define QTAB_US 2097152                 // 256 blocks * 4 c * 256 t * 8 shorts = 4 MB

typedef short short8 __attribute__((ext_vector_type(8)));
typedef float floatx4 __attribute__((ext_vector_type(4)));
typedef unsigned int uintx2 __attribute__((ext_vector_type(2)));
typedef unsigned int uintx4 __attribute__((ext_vector_type(4)));

__device__ inline unsigned short bf16r(float x) {
    unsigned int u = __builtin_bit_cast(unsigned int, x);
    u += 0x7fffu + ((u >> 16) & 1u);
    return (unsigned short)(u >> 16);
}
__device__ inline unsigned int pk_bf16(float a, float b) {
    return (unsigned int)bf16r(a) | ((unsigned int)bf16r(b) << 16);
}
__device__ inline float bf16tof(unsigned short h) {
    unsigned int u = ((unsigned int)h) << 16;
    return __builtin_bit_cast(float, u);
}

// ---------------- pre-pass: fp32 K/V -> bf16 tiles in LDS-ready swizzled layout ----------------
// grid 512 = b*128 + hkv*16 + kt. Tile base = bid*8192.
// Blocks with bid<256 additionally produce the sample-Q split-bf16 tables.
__global__ __launch_bounds__(256)
void convert_kernel(const float* __restrict__ Kp, const float* __restrict__ Vp,
                    const float* __restrict__ Qp,
                    unsigned short* __restrict__ Kb, unsigned short* __restrict__ Klo,
                    unsigned short* __restrict__ VTb,
                    unsigned short* __restrict__ Qh, unsigned short* __restrict__ Ql)
{
    int bid = blockIdx.x;
    int kt = bid & 15, hkv = (bid >> 4) & 7, b = bid >> 7;
    int t = threadIdx.x;
    size_t tile = (size_t)bid * TILE_US;

    // ---- K: hi + lo split (hi buffer doubles as attn's bf16 K) ----
    #pragma unroll
    for (int i = 0; i < 4; ++i) {
        int pos = t + 256 * i;
        int col = pos >> 4, gd = pos & 15;
        const float* kb = &Kp[((size_t)(b * L_ + kt * 64 + col) * HKV_ + hkv) * DH_ + gd * 8];
        float x[8];
        *(float4*)&x[0] = *(const float4*)kb;
        *(float4*)&x[4] = *(const float4*)(kb + 4);
        unsigned int gh[4], gl[4];
        #pragma unroll
        for (int j = 0; j < 4; ++j) {
            unsigned short h0 = bf16r(x[2*j]),   h1 = bf16r(x[2*j+1]);
            unsigned short l0 = bf16r(x[2*j]   - bf16tof(h0));
            unsigned short l1 = bf16r(x[2*j+1] - bf16tof(h1));
            gh[j] = (unsigned int)h0 | ((unsigned int)h1 << 16);
            gl[j] = (unsigned int)l0 | ((unsigned int)l1 << 16);
        }
        int phys = gd ^ (col & 15);
        *(uintx4*)&Kb[tile + col * 128 + phys * 8]  = (uintx4){gh[0], gh[1], gh[2], gh[3]};
        *(uintx4*)&Klo[tile + col * 128 + phys * 8] = (uintx4){gl[0], gl[1], gl[2], gl[3]};
    }

    // ---- V^T ----
    {
        int d4g = t & 31, g = t >> 5;    // g = k-granule (8 rows)
        const float* vb = &Vp[((size_t)(b * L_ + kt * 64 + g * 8) * HKV_ + hkv) * DH_ + d4g * 4];
        const size_t vs = (size_t)HKV_ * DH_;
        float4 r[8];
        #pragma unroll
        for (int j = 0; j < 8; ++j) r[j] = *(const float4*)(vb + (size_t)j * vs);
        #pragma unroll
        for (int ii = 0; ii < 4; ++ii) {
            int d = d4g * 4 + ii;
            int phys = g ^ (d & 7);
            uintx4 gp;
            gp[0] = pk_bf16(((const float*)&r[0])[ii], ((const float*)&r[1])[ii]);
            gp[1] = pk_bf16(((const float*)&r[2])[ii], ((const float*)&r[3])[ii]);
            gp[2] = pk_bf16(((const float*)&r[4])[ii], ((const float*)&r[5])[ii]);
            gp[3] = pk_bf16(((const float*)&r[6])[ii], ((const float*)&r[7])[ii]);
            *(uintx4*)&VTb[tile + d * 64 + phys * 8] = gp;
        }
    }

    // ---- sample-Q split frags (first 256 blocks) ----
    if (bid < 256) {
        int qts = bid & 1;
        int h   = (bid >> 1) & 31;
        int qb_ = bid >> 6;
        int w = t >> 6, l = t & 63, lm = l & 15, hq = l >> 4;
        int q0 = 896 + qts * 64;
        const float* qb = Qp + ((size_t)(qb_ * L_ + q0 + w * 16 + lm) * H_ + h) * DH_;
        #pragma unroll
        for (int c = 0; c < 4; ++c) {
            int dc = hq * 8 + 32 * c;
            float x[8];
            *(float4*)&x[0] = *(const float4*)(qb + dc);
            *(float4*)&x[4] = *(const float4*)(qb + dc + 4);
            short8 fh, fl;
            #pragma unroll
            for (int j = 0; j < 8; ++j) {
                float xs = x[j] * SCALE_;
                unsigned short hb = bf16r(xs);
                fh[j] = (short)hb;
                fl[j] = (short)bf16r(xs - bf16tof(hb));
            }
            size_t idx = (((size_t)bid * 4 + c) * 256 + t) * 8;
            *(short8*)&Qh[idx] = fh;
            *(short8*)&Ql[idx] = fl;
        }
    }
}

// ---------------- full causal attention, fixed-M bf16 MFMA flash (round-4 proven body) ---------
// grid 1024; XCD-chunked bijective swizzle (1024%8==0): each XCD owns 128 contiguous
// logical bids = 4 complete (b,hkv) groups -> K/V tables L2-resident per XCD.
// block 256 = 4 waves; phases qt=pr and qt=15-pr (uniform 17 tiles). LDS 40960 B -> 4 blocks/CU.
__global__ __launch_bounds__(256, 4)
void attn_mfma(const float* __restrict__ Qp, const unsigned short* __restrict__ Kbp,
               const unsigned short* __restrict__ VTp, float* __restrict__ Op)
{
    __shared__ __align__(16) unsigned short k_lds[64 * 128];   // [col][d], 16B-granule XOR swizzle by col&15
    __shared__ __align__(16) unsigned short vT[128 * 64];      // [d][k],  granule XOR swizzle by d&7
    __shared__ __align__(16) unsigned short p_lds[4 * 1024];   // per-wave [m][k], granule XOR by m&7

    int bid = (blockIdx.x & 7) * 128 + (blockIdx.x >> 3);      // XCD chunking
    int pr = bid & 7;
    int h  = (bid >> 3) & 31;
    int b  = bid >> 8;
    int hkv = h >> 2;
    int t = threadIdx.x;
    int w = t >> 6;
    int l = t & 63;
    int lm = l & 15;
    int hq = l >> 4;

    for (int ph = 0; ph < 2; ++ph) {
        int qt = ph ? (15 - pr) : pr;

        // Q A-frags (scale folded): A[m=lm][k=hq*8+j+32kc]
        short8 aq[4];
        {
            const float* qb = Qp + ((size_t)(b * L_ + qt * 64 + w * 16 + lm) * H_ + h) * DH_;
            #pragma unroll
            for (int c = 0; c < 4; ++c) {
                int dc = hq * 8 + 32 * c;
                float4 x0 = *(const float4*)(qb + dc);
                float4 x1 = *(const float4*)(qb + dc + 4);
                uintx4 packed;
                packed[0] = pk_bf16(x0.x * SCALE_, x0.y * SCALE_);
                packed[1] = pk_bf16(x0.z * SCALE_, x0.w * SCALE_);
                packed[2] = pk_bf16(x1.x * SCALE_, x1.y * SCALE_);
                packed[3] = pk_bf16(x1.z * SCALE_, x1.w * SCALE_);
                aq[c] = __builtin_bit_cast(short8, packed);
            }
        }

        floatx4 O[8];
        #pragma unroll
        for (int n = 0; n < 8; ++n) O[n] = (floatx4){0.f, 0.f, 0.f, 0.f};
        float l_acc[4] = {0.f, 0.f, 0.f, 0.f};

        for (int kt = 0; kt <= qt; ++kt) {
            __syncthreads();
            size_t tbase = (size_t)((b * HKV_ + hkv) * 16 + kt) * TILE_US;
            {
                const uintx4* kg = (const uintx4*)(Kbp + tbase) + t;
                const uintx4* vg = (const uintx4*)(VTp + tbase) + t;
                uintx4* kd = (uintx4*)k_lds + t;
                uintx4* vd = (uintx4*)vT + t;
                #pragma unroll
                for (int i = 0; i < 4; ++i) {
                    kd[i * 256] = kg[i * 256];
                    vd[i * 256] = vg[i * 256];
                }
            }
            __syncthreads();

            // QK^T: S[c] col n=lm <-> k_phys = lm*4+c ; C-init = -M (fixed-M softmax)
            floatx4 S[4];
            #pragma unroll
            for (int c = 0; c < 4; ++c) S[c] = (floatx4){-M_FIX, -M_FIX, -M_FIX, -M_FIX};
            #pragma unroll
            for (int kc = 0; kc < 4; ++kc) {
                #pragma unroll
                for (int c = 0; c < 4; ++c) {
                    int row = lm * 4 + c;
                    int phys = (kc * 4 + hq) ^ (row & 15);
                    short8 bk = *(const short8*)&k_lds[row * 128 + phys * 8];
                    S[c] = __builtin_amdgcn_mfma_f32_16x16x32_bf16(aq[kc], bk, S[c], 0, 0, 0);
                }
            }
            bool diag = (kt == qt);
            #pragma unroll
            for (int r = 0; r < 4; ++r) {
                float e0 = __expf(S[0][r]);
                float e1 = __expf(S[1][r]);
                float e2 = __expf(S[2][r]);
                float e3 = __expf(S[3][r]);
                if (diag) {
                    int qabs = qt * 64 + w * 16 + hq * 4 + r;
                    int kb0 = kt * 64 + lm * 4;
                    e0 = (kb0 + 0 <= qabs) ? e0 : 0.f;
                    e1 = (kb0 + 1 <= qabs) ? e1 : 0.f;
                    e2 = (kb0 + 2 <= qabs) ? e2 : 0.f;
                    e3 = (kb0 + 3 <= qabs) ? e3 : 0.f;
                }
                l_acc[r] += (e0 + e1) + (e2 + e3);
                int m = hq * 4 + r;
                int phys = (lm >> 1) ^ (m & 7);
                uintx2 gp;
                gp[0] = pk_bf16(e0, e1);
                gp[1] = pk_bf16(e2, e3);
                *(uintx2*)&p_lds[w * 1024 + m * 64 + phys * 8 + (lm & 1) * 4] = gp;
            }
            asm volatile("" ::: "memory");
            // PV as O^T = V^T * P^T  (A = V^T frag, B = P^T frag)
            int phys0 = hq ^ (lm & 7);
            int phys1 = (4 + hq) ^ (lm & 7);
            short8 bp0 = *(const short8*)&p_lds[w * 1024 + lm * 64 + phys0 * 8];
            short8 bp1 = *(const short8*)&p_lds[w * 1024 + lm * 64 + phys1 * 8];
            #pragma unroll
            for (int n = 0; n < 8; ++n) {
                int d = n * 16 + lm;
                short8 a0 = *(const short8*)&vT[d * 64 + (hq ^ (d & 7)) * 8];
                O[n] = __builtin_amdgcn_mfma_f32_16x16x32_bf16(a0, bp0, O[n], 0, 0, 0);
                short8 a1 = *(const short8*)&vT[d * 64 + (((4 + hq) ^ (d & 7))) * 8];
                O[n] = __builtin_amdgcn_mfma_f32_16x16x32_bf16(a1, bp1, O[n], 0, 0, 0);
            }
        }
        // one-time l reduce + broadcast via p_lds (own-wave region)
        #pragma unroll
        for (int r = 0; r < 4; ++r) {
            l_acc[r] += __shfl_xor(l_acc[r], 1);
            l_acc[r] += __shfl_xor(l_acc[r], 2);
            l_acc[r] += __shfl_xor(l_acc[r], 4);
            l_acc[r] += __shfl_xor(l_acc[r], 8);
        }
        float* lf = (float*)&p_lds[w * 1024];
        if (lm == 0) {
            #pragma unroll
            for (int r = 0; r < 4; ++r) lf[hq * 4 + r] = l_acc[r];
        }
        asm volatile("" ::: "memory");
        __builtin_amdgcn_wave_barrier();
        float invl = 1.0f / lf[lm];
        // O^T epilogue: lane owns q = w*16+lm, d = n*16+hq*4..+3 -> float4 stores
        #pragma unroll
        for (int n = 0; n < 8; ++n) {
            float4 res;
            res.x = O[n][0] * invl; res.y = O[n][1] * invl;
            res.z = O[n][2] * invl; res.w = O[n][3] * invl;
            *(float4*)&Op[((size_t)(b * L_ + qt * 64 + w * 16 + lm) * H_ + h) * DH_ + n * 16 + hq * 4] = res;
        }
    }
}

// ---------------- importance A: chunked partial row-sums (kept from round 8, ~17us win) -------
// grid 1024 = (b,h,qts,chunk). Block processes tiles kt in [chunk*4, min(chunk*4+3, ktd)],
// writes per-chunk partial sums lpart[(qblock*64 + row)*4 + chunk]. Deterministic combine
// happens in imp_col (fixed order), so no atomics and no init needed (every slot written).
__global__ __launch_bounds__(256)
void imp_lsum_kernel(const unsigned short* __restrict__ Qhp, const unsigned short* __restrict__ Qlp,
                     const unsigned short* __restrict__ Kbp, const unsigned short* __restrict__ Klop,
                     float* __restrict__ lpart)
{
    __shared__ __align__(16) unsigned short khi[64 * 128];
    __shared__ __align__(16) unsigned short klo[64 * 128];

    int bid = blockIdx.x;
    int chunk = bid & 3;
    int qts = (bid >> 2) & 1;
    int h   = (bid >> 3) & 31;
    int b   = bid >> 8;
    int hkv = h >> 2;
    int qblock = (b * 32 + h) * 2 + qts;
    int t = threadIdx.x;
    int w = t >> 6;
    int l = t & 63;
    int lm = l & 15;
    int hq = l >> 4;
    int q0 = 896 + qts * 64;
    int ktd = q0 >> 6;
    int kt_lo = chunk * 4;
    int kt_hi = min(kt_lo + 3, ktd);

    short8 aqh[4], aql[4];
    #pragma unroll
    for (int c = 0; c < 4; ++c) {
        size_t idx = (((size_t)qblock * 4 + c) * 256 + t) * 8;
        aqh[c] = *(const short8*)&Qhp[idx];
        aql[c] = *(const short8*)&Qlp[idx];
    }

    float l_acc[4] = {0.f, 0.f, 0.f, 0.f};
    for (int kt = kt_lo; kt <= kt_hi; ++kt) {
        __syncthreads();
        size_t tbase = (size_t)((b * HKV_ + hkv) * 16 + kt) * TILE_US;
        {
            const uintx4* hg = (const uintx4*)(Kbp + tbase) + t;
            const uintx4* lg = (const uintx4*)(Klop + tbase) + t;
            uintx4* hd = (uintx4*)khi + t;
            uintx4* ld = (uintx4*)klo + t;
            #pragma unroll
            for (int i = 0; i < 4; ++i) {
                hd[i * 256] = hg[i * 256];
                ld[i * 256] = lg[i * 256];
            }
        }
        __syncthreads();

        floatx4 S[4];
        #pragma unroll
        for (int c = 0; c < 4; ++c) S[c] = (floatx4){-M_FIX, -M_FIX, -M_FIX, -M_FIX};
        #pragma unroll
        for (int kc = 0; kc < 4; ++kc) {
            #pragma unroll
            for (int c = 0; c < 4; ++c) {
                int row = lm * 4 + c;
                int phys = (kc * 4 + hq) ^ (row & 15);
                short8 bh = *(const short8*)&khi[row * 128 + phys * 8];
                short8 bl = *(const short8*)&klo[row * 128 + phys * 8];
                S[c] = __builtin_amdgcn_mfma_f32_16x16x32_bf16(aqh[kc], bh, S[c], 0, 0, 0);
                S[c] = __builtin_amdgcn_mfma_f32_16x16x32_bf16(aqh[kc], bl, S[c], 0, 0, 0);
                S[c] = __builtin_amdgcn_mfma_f32_16x16x32_bf16(aql[kc], bh, S[c], 0, 0, 0);
            }
        }
        bool diag = (kt == ktd);
        #pragma unroll
        for (int r = 0; r < 4; ++r) {
            int qabs = q0 + w * 16 + hq * 4 + r;
            #pragma unroll
            for (int c = 0; c < 4; ++c) {
                float ev = __expf(S[c][r]);
                if (diag) {
                    int kabs = kt * 64 + lm * 4 + c;
                    ev = (kabs <= qabs) ? ev : 0.f;
                }
                l_acc[r] += ev;
            }
        }
    }
    #pragma unroll
    for (int r = 0; r < 4; ++r) {
        l_acc[r] += __shfl_xor(l_acc[r], 1);
        l_acc[r] += __shfl_xor(l_acc[r], 2);
        l_acc[r] += __shfl_xor(l_acc[r], 4);
        l_acc[r] += __shfl_xor(l_acc[r], 8);
    }
    if (lm == 0) {
        #pragma unroll
        for (int r = 0; r < 4; ++r) {
            int row = w * 16 + hq * 4 + r;
            lpart[((size_t)qblock * 64 + row) * 4 + chunk] = l_acc[r];
        }
    }
}

// ---------------- importance B: column sums per (b,h,kt), XCD-chunked ----------------
// grid 2048 (2048%8==0, bijective); 256-bid chunks per XCD -> K tables L2-resident.
__global__ __launch_bounds__(256, 4)
void imp_col_kernel(const unsigned short* __restrict__ Qhp, const unsigned short* __restrict__ Qlp,
                    const unsigned short* __restrict__ Kbp, const unsigned short* __restrict__ Klop,
                    const float* __restrict__ lpart, float* __restrict__ imp)
{
    __shared__ __align__(16) unsigned short khi[64 * 128];
    __shared__ __align__(16) unsigned short klo[64 * 128];
    __shared__ float imp_loc[64];

    int bid = (blockIdx.x & 7) * 256 + (blockIdx.x >> 3);   // XCD chunking
    int kt = bid & 15;
    int h  = (bid >> 4) & 31;
    int b  = bid >> 9;
    int hkv = h >> 2;
    int t = threadIdx.x;
    int w = t >> 6;
    int l = t & 63;
    int lm = l & 15;
    int hq = l >> 4;

    if (t < 64) imp_loc[t] = 0.f;
    size_t tbase = (size_t)((b * HKV_ + hkv) * 16 + kt) * TILE_US;
    {
        const uintx4* hg = (const uintx4*)(Kbp + tbase) + t;
        const uintx4* lg = (const uintx4*)(Klop + tbase) + t;
        uintx4* hd = (uintx4*)khi + t;
        uintx4* ld = (uintx4*)klo + t;
        #pragma unroll
        for (int i = 0; i < 4; ++i) {
            hd[i * 256] = hg[i * 256];
            ld[i * 256] = lg[i * 256];
        }
    }
    __syncthreads();

    float cs[4] = {0.f, 0.f, 0.f, 0.f};
    for (int qp2 = 0; qp2 < 2; ++qp2) {
        if (kt == 15 && qp2 == 0) continue;
        int qbid = (b * 32 + h) * 2 + qp2;
        int q0 = 896 + qp2 * 64;
        short8 aqh[4], aql[4];
        #pragma unroll
        for (int c = 0; c < 4; ++c) {
            size_t idx = (((size_t)qbid * 4 + c) * 256 + t) * 8;
            aqh[c] = *(const short8*)&Qhp[idx];
            aql[c] = *(const short8*)&Qlp[idx];
        }
        floatx4 iv4;
        #pragma unroll
        for (int r = 0; r < 4; ++r) {
            int row = w * 16 + hq * 4 + r;
            float4 p = *(const float4*)&lpart[((size_t)qbid * 64 + row) * 4];
            iv4[r] = 1.0f / ((p.x + p.y) + (p.z + p.w));
        }

        floatx4 S[4];
        #pragma unroll
        for (int c = 0; c < 4; ++c) S[c] = (floatx4){-M_FIX, -M_FIX, -M_FIX, -M_FIX};
        #pragma unroll
        for (int kc = 0; kc < 4; ++kc) {
            #pragma unroll
            for (int c = 0; c < 4; ++c) {
                int row = lm * 4 + c;
                int phys = (kc * 4 + hq) ^ (row & 15);
                short8 bh = *(const short8*)&khi[row * 128 + phys * 8];
                short8 bl = *(const short8*)&klo[row * 128 + phys * 8];
                S[c] = __builtin_amdgcn_mfma_f32_16x16x32_bf16(aqh[kc], bh, S[c], 0, 0, 0);
                S[c] = __builtin_amdgcn_mfma_f32_16x16x32_bf16(aqh[kc], bl, S[c], 0, 0, 0);
                S[c] = __builtin_amdgcn_mfma_f32_16x16x32_bf16(aql[kc], bh, S[c], 0, 0, 0);
            }
        }
        #pragma unroll
        for (int c = 0; c < 4; ++c) {
            int kabs = kt * 64 + lm * 4 + c;
            #pragma unroll
            for (int r = 0; r < 4; ++r) {
                int qabs = q0 + w * 16 + hq * 4 + r;
                float ev = (kabs <= qabs) ? __expf(S[c][r]) : 0.f;
                cs[c] += ev * iv4[r];
            }
        }
    }
    #pragma unroll
    for (int c = 0; c < 4; ++c) {
        cs[c] += __shfl_xor(cs[c], 16);
        cs[c] += __shfl_xor(cs[c], 32);
    }
    if (l < 16) {
        #pragma unroll
        for (int c = 0; c < 4; ++c) atomicAdd(&imp_loc[lm * 4 + c], cs[c]);
    }
    __syncthreads();
    if (t < 64) atomicAdd(&imp[b * L_ + kt * 64 + t], imp_loc[t]);
}

// ---------------- top-k 512 of 1024 per batch; optionally emits inverse slot map ----------------
__global__ void topk_kernel(const float* __restrict__ imp, const int* __restrict__ slot_mapping,
                            int* __restrict__ keep, int* __restrict__ inv)
{
    __shared__ float vals[1024];
    __shared__ int   idxs[1024];
    int b = blockIdx.x;
    int t = threadIdx.x;   // 512 threads
    for (int i = t; i < 1024; i += 512) { vals[i] = imp[b * L_ + i]; idxs[i] = i; }

    for (int size = 2; size <= 1024; size <<= 1) {
        for (int stride = size >> 1; stride > 0; stride >>= 1) {
            __syncthreads();
            for (int i = t; i < 1024; i += 512) {
                int j = i ^ stride;
                if (j > i) {
                    float vi = vals[i], vj = vals[j];
                    int ii = idxs[i], ij = idxs[j];
                    bool j_before_i = (vj > vi) || (vj == vi && ij < ii);
                    bool descRegion = ((i & size) == 0);
                    bool doSwap = descRegion ? j_before_i : !j_before_i;
                    if (doSwap) {
                        vals[i] = vj; vals[j] = vi;
                        idxs[i] = ij; idxs[j] = ii;
                    }
                }
            }
        }
    }
    __syncthreads();
    for (int size = 2; size <= 512; size <<= 1) {
        for (int stride = size >> 1; stride > 0; stride >>= 1) {
            __syncthreads();
            int i = t, j = t ^ stride;
            if (j > i) {
                int a = idxs[i], bb = idxs[j];
                bool ascRegion = ((i & size) == 0);
                bool doSwap = ascRegion ? (a > bb) : (a < bb);
                if (doSwap) { idxs[i] = bb; idxs[j] = a; }
            }
        }
    }
    __syncthreads();
    keep[b * KEEP_ + t] = idxs[t];
    if (inv) {
        int dest = slot_mapping[b * L_ + t];        // j = t < 512
        inv[dest] = b * L_ + idxs[t];               // global source row
    }
}

// ---------------- fused cache output: every slot written exactly once ----------------
__global__ __launch_bounds__(256)
void cache_out_kernel(const float* __restrict__ kin, const float* __restrict__ vin,
                      const float* __restrict__ kc_in, const float* __restrict__ vc_in,
                      const int* __restrict__ inv,
                      float* __restrict__ kc_out, float* __restrict__ vc_out)
{
    int bid = blockIdx.x;
    int t = threadIdx.x;
    #pragma unroll
    for (int i = 0; i < 4; ++i) {
        int s = bid * 4 + i;
        int src = inv[s];
        const float4* kp = (src >= 0) ? (const float4*)&kin[(size_t)src * 1024]
                                      : (const float4*)&kc_in[(size_t)s * 1024];
        const float4* vp = (src >= 0) ? (const float4*)&vin[(size_t)src * 1024]
                                      : (const float4*)&vc_in[(size_t)s * 1024];
        ((float4*)&kc_out[(size_t)s * 1024])[t] = kp[t];
        ((float4*)&vc_out[(size_t)s * 1024])[t] = vp[t];
    }
}

// ---------------- fallback pair (used only if workspace too small for inv) ----------------
__global__ __launch_bounds__(256)
void cache_copy_kernel(const float* __restrict__ kc_in, const float* __restrict__ vc_in,
                       float* __restrict__ kc_out, float* __restrict__ vc_out)
{
    size_t idx = (size_t)blockIdx.x * 256 + threadIdx.x;
    const float4* ki = (const float4*)kc_in;
    const float4* vi = (const float4*)vc_in;
    float4* ko = (float4*)kc_out;
    float4* vo = (float4*)vc_out;
    #pragma unroll
    for (int i = 0; i < 4; ++i) {
        size_t off = idx + (size_t)i * 524288;
        ko[off] = ki[off];
        vo[off] = vi[off];
    }
}

__global__ void scatter_kernel(const float* __restrict__ kin, const float* __restrict__ vin,
                               const int* __restrict__ keep, const int* __restrict__ slot_mapping,
                               float* __restrict__ kc_out, float* __restrict__ vc_out)
{
    int bid = blockIdx.x;
    int b = bid >> 9, j = bid & 511;
    int src = b * L_ + keep[b * KEEP_ + j];
    int dst = slot_mapping[b * L_ + j];
    int t = threadIdx.x;
    float4 kv = *(const float4*)&kin[(size_t)src * 1024 + t * 4];
    *(float4*)&kc_out[(size_t)dst * 1024 + t * 4] = kv;
    float4 vv = *(const float4*)&vin[(size_t)src * 1024 + t * 4];
    *(float4*)&vc_out[(size_t)dst * 1024 + t * 4] = vv;
}

extern "C" void kernel_launch(void* const* d_in, const int* in_sizes, int n_in,
                              void* d_out, int out_size, void* d_ws, size_t ws_size,
                              hipStream_t stream)
{
    const float* q = (const float*)d_in[0];
    const float* k = (const float*)d_in[1];
    const float* v = (const float*)d_in[2];
    const float* k_cache = (const float*)d_in[3];
    const float* v_cache = (const float*)d_in[4];
    const int* slot_mapping = (const int*)d_in[5];

    float* o = (float*)d_out;
    float* kc_out = o + O_ELEMS;
    float* vc_out = kc_out + CACHE_ELEMS;

    // workspace: imp 16K | keep 8K | (unused 64K) | inv 32K  (120 KB)
    float* imp  = (float*)d_ws;                    // 4096 f
    int*   keep = (int*)(imp + B_ * L_);           // 2048 i
    float* invL = (float*)(keep + B_ * KEEP_);     // 16384 f (layout-compat spacer)
    int*   inv  = (int*)(invL + B_ * H_ * 128);    // 8192 i @ 88 KB
    bool use_inv = ws_size >= (size_t)(120 * 1024);
    if (!use_inv) inv = nullptr;

    // lpart (256 KB partial row-sums) lives in the kc_out output region, which is
    // untouched until cache-out time (after all lpart consumers).
    float* lpart = kc_out;

    // bf16 staging scratch (32 MB): Kb/Klo/VTb 8MB each + Qh/Ql 4MB each.
    const size_t SCRATCH_US = (size_t)3 * 512 * TILE_US + (size_t)2 * QTAB_US;
    bool ws_fits = ws_size >= (size_t)(128 * 1024) + SCRATCH_US * sizeof(unsigned short);
    unsigned short* Kb = ws_fits ? (unsigned short*)((char*)d_ws + 128 * 1024)
                                 : (unsigned short*)vc_out;
    unsigned short* Klo = Kb  + (size_t)512 * TILE_US;
    unsigned short* VTb = Klo + (size_t)512 * TILE_US;
    unsigned short* Qh  = VTb + (size_t)512 * TILE_US;
    unsigned short* Ql  = Qh  + (size_t)QTAB_US;

    (void)hipMemsetAsync(imp, 0, B_ * L_ * 4, stream);
    if (use_inv) (void)hipMemsetAsync(inv, 0xFF, 8192 * 4, stream);   // -1 sentinel

    convert_kernel<<<dim3(512), dim3(256), 0, stream>>>(k, v, q, Kb, Klo, VTb, Qh, Ql);
    attn_mfma<<<dim3(1024), dim3(256), 0, stream>>>(q, Kb, VTb, o);
    imp_lsum_kernel<<<dim3(1024), dim3(256), 0, stream>>>(Qh, Ql, Kb, Klo, lpart);
    imp_col_kernel<<<dim3(2048), dim3(256), 0, stream>>>(Qh, Ql, Kb, Klo, lpart, imp);
    topk_kernel<<<dim3(4), dim3(512), 0, stream>>>(imp, slot_mapping, keep, inv);

    if (use_inv) {
        cache_out_kernel<<<dim3(2048), dim3(256), 0, stream>>>(k, v, k_cache, v_cache, inv, kc_out, vc_out);
    } else {
        cache_copy_kernel<<<dim3(2048), dim3(256), 0, stream>>>(k_cache, v_cache, kc_out, vc_out);
        scatter_kernel<<<dim3(2048), dim3(256), 0, stream>>>(k, v, keep, slot_mapping, kc_out, vc_out);
    }
}

// Round 10
// 387.571 us; speedup vs baseline: 1.1772x; 1.0212x over previous
//
#include <hip/hip_runtime.h>

#define B_ 4
#define L_ 1024
#define H_ 32
#define HKV_ 8
#define DH_ 128
#define SCALE_ 0.08838834764831845f
#define M_FIX 20.0f
#define KEEP_ 512
#define O_ELEMS (B_*L_*H_*DH_)          // 16777216
#define CACHE_ELEMS (8192*HKV_*DH_)     // 8388608
#define TILE_US 8192                    // 64*128 bf16 elems per staged tile
#define QTAB_US 2097152                 // 256 blocks * 4 c * 256 t * 8 shorts = 4 MB

typedef short short8 __attribute__((ext_vector_type(8)));
typedef float floatx4 __attribute__((ext_vector_type(4)));
typedef unsigned int uintx2 __attribute__((ext_vector_type(2)));
typedef unsigned int uintx4 __attribute__((ext_vector_type(4)));

__device__ inline unsigned short bf16r(float x) {
    unsigned int u = __builtin_bit_cast(unsigned int, x);
    u += 0x7fffu + ((u >> 16) & 1u);
    return (unsigned short)(u >> 16);
}
__device__ inline unsigned int pk_bf16(float a, float b) {
    return (unsigned int)bf16r(a) | ((unsigned int)bf16r(b) << 16);
}
__device__ inline float bf16tof(unsigned short h) {
    unsigned int u = ((unsigned int)h) << 16;
    return __builtin_bit_cast(float, u);
}

// ---------------- pre-pass: fp32 K/V -> bf16 tiles in LDS-ready swizzled layout ----------------
// grid 512 = b*128 + hkv*16 + kt. Tile base = bid*8192.
// Blocks with bid<256 additionally produce the sample-Q split-bf16 tables.
__global__ __launch_bounds__(256)
void convert_kernel(const float* __restrict__ Kp, const float* __restrict__ Vp,
                    const float* __restrict__ Qp,
                    unsigned short* __restrict__ Kb, unsigned short* __restrict__ Klo,
                    unsigned short* __restrict__ VTb,
                    unsigned short* __restrict__ Qh, unsigned short* __restrict__ Ql)
{
    int bid = blockIdx.x;
    int kt = bid & 15, hkv = (bid >> 4) & 7, b = bid >> 7;
    int t = threadIdx.x;
    size_t tile = (size_t)bid * TILE_US;

    // ---- K: hi + lo split (hi buffer doubles as attn's bf16 K) ----
    #pragma unroll
    for (int i = 0; i < 4; ++i) {
        int pos = t + 256 * i;
        int col = pos >> 4, gd = pos & 15;
        const float* kb = &Kp[((size_t)(b * L_ + kt * 64 + col) * HKV_ + hkv) * DH_ + gd * 8];
        float x[8];
        *(float4*)&x[0] = *(const float4*)kb;
        *(float4*)&x[4] = *(const float4*)(kb + 4);
        unsigned int gh[4], gl[4];
        #pragma unroll
        for (int j = 0; j < 4; ++j) {
            unsigned short h0 = bf16r(x[2*j]),   h1 = bf16r(x[2*j+1]);
            unsigned short l0 = bf16r(x[2*j]   - bf16tof(h0));
            unsigned short l1 = bf16r(x[2*j+1] - bf16tof(h1));
            gh[j] = (unsigned int)h0 | ((unsigned int)h1 << 16);
            gl[j] = (unsigned int)l0 | ((unsigned int)l1 << 16);
        }
        int phys = gd ^ (col & 15);
        *(uintx4*)&Kb[tile + col * 128 + phys * 8]  = (uintx4){gh[0], gh[1], gh[2], gh[3]};
        *(uintx4*)&Klo[tile + col * 128 + phys * 8] = (uintx4){gl[0], gl[1], gl[2], gl[3]};
    }

    // ---- V^T ----
    {
        int d4g = t & 31, g = t >> 5;    // g = k-granule (8 rows)
        const float* vb = &Vp[((size_t)(b * L_ + kt * 64 + g * 8) * HKV_ + hkv) * DH_ + d4g * 4];
        const size_t vs = (size_t)HKV_ * DH_;
        float4 r[8];
        #pragma unroll
        for (int j = 0; j < 8; ++j) r[j] = *(const float4*)(vb + (size_t)j * vs);
        #pragma unroll
        for (int ii = 0; ii < 4; ++ii) {
            int d = d4g * 4 + ii;
            int phys = g ^ (d & 7);
            uintx4 gp;
            gp[0] = pk_bf16(((const float*)&r[0])[ii], ((const float*)&r[1])[ii]);
            gp[1] = pk_bf16(((const float*)&r[2])[ii], ((const float*)&r[3])[ii]);
            gp[2] = pk_bf16(((const float*)&r[4])[ii], ((const float*)&r[5])[ii]);
            gp[3] = pk_bf16(((const float*)&r[6])[ii], ((const float*)&r[7])[ii]);
            *(uintx4*)&VTb[tile + d * 64 + phys * 8] = gp;
        }
    }

    // ---- sample-Q split frags (first 256 blocks) ----
    if (bid < 256) {
        int qts = bid & 1;
        int h   = (bid >> 1) & 31;
        int qb_ = bid >> 6;
        int w = t >> 6, l = t & 63, lm = l & 15, hq = l >> 4;
        int q0 = 896 + qts * 64;
        const float* qb = Qp + ((size_t)(qb_ * L_ + q0 + w * 16 + lm) * H_ + h) * DH_;
        #pragma unroll
        for (int c = 0; c < 4; ++c) {
            int dc = hq * 8 + 32 * c;
            float x[8];
            *(float4*)&x[0] = *(const float4*)(qb + dc);
            *(float4*)&x[4] = *(const float4*)(qb + dc + 4);
            short8 fh, fl;
            #pragma unroll
            for (int j = 0; j < 8; ++j) {
                float xs = x[j] * SCALE_;
                unsigned short hb = bf16r(xs);
                fh[j] = (short)hb;
                fl[j] = (short)bf16r(xs - bf16tof(hb));
            }
            size_t idx = (((size_t)bid * 4 + c) * 256 + t) * 8;
            *(short8*)&Qh[idx] = fh;
            *(short8*)&Ql[idx] = fl;
        }
    }
}

// ---------------- full causal attention: 8-wave / 2-head blocks sharing K/V staging ------------
// grid 512 = b(4) x hkv(8) x hp(2) x pr(8), XCD-chunked (512%8==0; 64-bid chunks = 4 complete
// (b,hkv) groups per XCD). Waves 0-3 -> head hkv*4+hp*2, waves 4-7 -> +1: one 32KB K/V staging
// feeds 2x the MFMA of the 4-wave version. Per-thread body identical to the proven round-4 loop
// (same VGPR footprint -> no spill). LDS 16K K + 16K V + 16K P(8 waves) = 48KB -> 2 blocks/CU.
__global__ __launch_bounds__(512, 4)
void attn_mfma(const float* __restrict__ Qp, const unsigned short* __restrict__ Kbp,
               const unsigned short* __restrict__ VTp, float* __restrict__ Op)
{
    __shared__ __align__(16) unsigned short k_lds[64 * 128];   // [col][d], 16B-granule XOR swizzle by col&15
    __shared__ __align__(16) unsigned short vT[128 * 64];      // [d][k],  granule XOR swizzle by d&7
    __shared__ __align__(16) unsigned short p_lds[8 * 1024];   // per-wave [m][k], granule XOR by m&7

    int bid = (blockIdx.x & 7) * 64 + (blockIdx.x >> 3);       // XCD chunking, bijective
    int pr  = bid & 7;
    int hp  = (bid >> 3) & 1;
    int hkv = (bid >> 4) & 7;
    int b   = bid >> 7;
    int t = threadIdx.x;        // 0..511
    int w = t >> 6;             // wave 0..7
    int l = t & 63;
    int lm = l & 15;
    int hq = l >> 4;
    int h  = hkv * 4 + hp * 2 + (w >> 2);   // this wave's head
    int wi = w & 3;                          // wave-in-head: q-row group

    for (int ph = 0; ph < 2; ++ph) {
        int qt = ph ? (15 - pr) : pr;

        // Q A-frags (scale folded): A[m=lm][k=hq*8+j+32kc]
        short8 aq[4];
        {
            const float* qb = Qp + ((size_t)(b * L_ + qt * 64 + wi * 16 + lm) * H_ + h) * DH_;
            #pragma unroll
            for (int c = 0; c < 4; ++c) {
                int dc = hq * 8 + 32 * c;
                float4 x0 = *(const float4*)(qb + dc);
                float4 x1 = *(const float4*)(qb + dc + 4);
                uintx4 packed;
                packed[0] = pk_bf16(x0.x * SCALE_, x0.y * SCALE_);
                packed[1] = pk_bf16(x0.z * SCALE_, x0.w * SCALE_);
                packed[2] = pk_bf16(x1.x * SCALE_, x1.y * SCALE_);
                packed[3] = pk_bf16(x1.z * SCALE_, x1.w * SCALE_);
                aq[c] = __builtin_bit_cast(short8, packed);
            }
        }

        floatx4 O[8];
        #pragma unroll
        for (int n = 0; n < 8; ++n) O[n] = (floatx4){0.f, 0.f, 0.f, 0.f};
        float l_acc[4] = {0.f, 0.f, 0.f, 0.f};

        for (int kt = 0; kt <= qt; ++kt) {
            __syncthreads();
            size_t tbase = (size_t)((b * HKV_ + hkv) * 16 + kt) * TILE_US;
            {
                // 1024 uintx4 per table, 512 threads -> 2 K + 2 V loads/thread
                const uintx4* kg = (const uintx4*)(Kbp + tbase) + t;
                const uintx4* vg = (const uintx4*)(VTp + tbase) + t;
                uintx4* kd = (uintx4*)k_lds + t;
                uintx4* vd = (uintx4*)vT + t;
                #pragma unroll
                for (int i = 0; i < 2; ++i) {
                    kd[i * 512] = kg[i * 512];
                    vd[i * 512] = vg[i * 512];
                }
            }
            __syncthreads();

            // QK^T: S[c] col n=lm <-> k_phys = lm*4+c ; C-init = -M (fixed-M softmax)
            floatx4 S[4];
            #pragma unroll
            for (int c = 0; c < 4; ++c) S[c] = (floatx4){-M_FIX, -M_FIX, -M_FIX, -M_FIX};
            #pragma unroll
            for (int kc = 0; kc < 4; ++kc) {
                #pragma unroll
                for (int c = 0; c < 4; ++c) {
                    int row = lm * 4 + c;
                    int phys = (kc * 4 + hq) ^ (row & 15);
                    short8 bk = *(const short8*)&k_lds[row * 128 + phys * 8];
                    S[c] = __builtin_amdgcn_mfma_f32_16x16x32_bf16(aq[kc], bk, S[c], 0, 0, 0);
                }
            }
            bool diag = (kt == qt);
            #pragma unroll
            for (int r = 0; r < 4; ++r) {
                float e0 = __expf(S[0][r]);
                float e1 = __expf(S[1][r]);
                float e2 = __expf(S[2][r]);
                float e3 = __expf(S[3][r]);
                if (diag) {
                    int qabs = qt * 64 + wi * 16 + hq * 4 + r;
                    int kb0 = kt * 64 + lm * 4;
                    e0 = (kb0 + 0 <= qabs) ? e0 : 0.f;
                    e1 = (kb0 + 1 <= qabs) ? e1 : 0.f;
                    e2 = (kb0 + 2 <= qabs) ? e2 : 0.f;
                    e3 = (kb0 + 3 <= qabs) ? e3 : 0.f;
                }
                l_acc[r] += (e0 + e1) + (e2 + e3);
                int m = hq * 4 + r;
                int phys = (lm >> 1) ^ (m & 7);
                uintx2 gp;
                gp[0] = pk_bf16(e0, e1);
                gp[1] = pk_bf16(e2, e3);
                *(uintx2*)&p_lds[w * 1024 + m * 64 + phys * 8 + (lm & 1) * 4] = gp;
            }
            asm volatile("" ::: "memory");
            // PV as O^T = V^T * P^T  (A = V^T frag, B = P^T frag)
            int phys0 = hq ^ (lm & 7);
            int phys1 = (4 + hq) ^ (lm & 7);
            short8 bp0 = *(const short8*)&p_lds[w * 1024 + lm * 64 + phys0 * 8];
            short8 bp1 = *(const short8*)&p_lds[w * 1024 + lm * 64 + phys1 * 8];
            #pragma unroll
            for (int n = 0; n < 8; ++n) {
                int d = n * 16 + lm;
                short8 a0 = *(const short8*)&vT[d * 64 + (hq ^ (d & 7)) * 8];
                O[n] = __builtin_amdgcn_mfma_f32_16x16x32_bf16(a0, bp0, O[n], 0, 0, 0);
                short8 a1 = *(const short8*)&vT[d * 64 + (((4 + hq) ^ (d & 7))) * 8];
                O[n] = __builtin_amdgcn_mfma_f32_16x16x32_bf16(a1, bp1, O[n], 0, 0, 0);
            }
        }
        // one-time l reduce + broadcast via p_lds (own-wave region)
        #pragma unroll
        for (int r = 0; r < 4; ++r) {
            l_acc[r] += __shfl_xor(l_acc[r], 1);
            l_acc[r] += __shfl_xor(l_acc[r], 2);
            l_acc[r] += __shfl_xor(l_acc[r], 4);
            l_acc[r] += __shfl_xor(l_acc[r], 8);
        }
        float* lf = (float*)&p_lds[w * 1024];
        if (lm == 0) {
            #pragma unroll
            for (int r = 0; r < 4; ++r) lf[hq * 4 + r] = l_acc[r];
        }
        asm volatile("" ::: "memory");
        __builtin_amdgcn_wave_barrier();
        float invl = 1.0f / lf[lm];
        // O^T epilogue: lane owns q = wi*16+lm, d = n*16+hq*4..+3 -> float4 stores
        #pragma unroll
        for (int n = 0; n < 8; ++n) {
            float4 res;
            res.x = O[n][0] * invl; res.y = O[n][1] * invl;
            res.z = O[n][2] * invl; res.w = O[n][3] * invl;
            *(float4*)&Op[((size_t)(b * L_ + qt * 64 + wi * 16 + lm) * H_ + h) * DH_ + n * 16 + hq * 4] = res;
        }
    }
}

// ---------------- importance A: chunked partial row-sums ----------------
// grid 1024 = (b,h,qts,chunk). Block processes tiles kt in [chunk*4, min(chunk*4+3, ktd)],
// writes per-chunk partial sums lpart[(qblock*64 + row)*4 + chunk]. Deterministic combine
// happens in imp_col (fixed order), so no atomics and no init needed (every slot written).
__global__ __launch_bounds__(256)
void imp_lsum_kernel(const unsigned short* __restrict__ Qhp, const unsigned short* __restrict__ Qlp,
                     const unsigned short* __restrict__ Kbp, const unsigned short* __restrict__ Klop,
                     float* __restrict__ lpart)
{
    __shared__ __align__(16) unsigned short khi[64 * 128];
    __shared__ __align__(16) unsigned short klo[64 * 128];

    int bid = blockIdx.x;
    int chunk = bid & 3;
    int qts = (bid >> 2) & 1;
    int h   = (bid >> 3) & 31;
    int b   = bid >> 8;
    int hkv = h >> 2;
    int qblock = (b * 32 + h) * 2 + qts;
    int t = threadIdx.x;
    int w = t >> 6;
    int l = t & 63;
    int lm = l & 15;
    int hq = l >> 4;
    int q0 = 896 + qts * 64;
    int ktd = q0 >> 6;
    int kt_lo = chunk * 4;
    int kt_hi = min(kt_lo + 3, ktd);

    short8 aqh[4], aql[4];
    #pragma unroll
    for (int c = 0; c < 4; ++c) {
        size_t idx = (((size_t)qblock * 4 + c) * 256 + t) * 8;
        aqh[c] = *(const short8*)&Qhp[idx];
        aql[c] = *(const short8*)&Qlp[idx];
    }

    float l_acc[4] = {0.f, 0.f, 0.f, 0.f};
    for (int kt = kt_lo; kt <= kt_hi; ++kt) {
        __syncthreads();
        size_t tbase = (size_t)((b * HKV_ + hkv) * 16 + kt) * TILE_US;
        {
            const uintx4* hg = (const uintx4*)(Kbp + tbase) + t;
            const uintx4* lg = (const uintx4*)(Klop + tbase) + t;
            uintx4* hd = (uintx4*)khi + t;
            uintx4* ld = (uintx4*)klo + t;
            #pragma unroll
            for (int i = 0; i < 4; ++i) {
                hd[i * 256] = hg[i * 256];
                ld[i * 256] = lg[i * 256];
            }
        }
        __syncthreads();

        floatx4 S[4];
        #pragma unroll
        for (int c = 0; c < 4; ++c) S[c] = (floatx4){-M_FIX, -M_FIX, -M_FIX, -M_FIX};
        #pragma unroll
        for (int kc = 0; kc < 4; ++kc) {
            #pragma unroll
            for (int c = 0; c < 4; ++c) {
                int row = lm * 4 + c;
                int phys = (kc * 4 + hq) ^ (row & 15);
                short8 bh = *(const short8*)&khi[row * 128 + phys * 8];
                short8 bl = *(const short8*)&klo[row * 128 + phys * 8];
                S[c] = __builtin_amdgcn_mfma_f32_16x16x32_bf16(aqh[kc], bh, S[c], 0, 0, 0);
                S[c] = __builtin_amdgcn_mfma_f32_16x16x32_bf16(aqh[kc], bl, S[c], 0, 0, 0);
                S[c] = __builtin_amdgcn_mfma_f32_16x16x32_bf16(aql[kc], bh, S[c], 0, 0, 0);
            }
        }
        bool diag = (kt == ktd);
        #pragma unroll
        for (int r = 0; r < 4; ++r) {
            int qabs = q0 + w * 16 + hq * 4 + r;
            #pragma unroll
            for (int c = 0; c < 4; ++c) {
                float ev = __expf(S[c][r]);
                if (diag) {
                    int kabs = kt * 64 + lm * 4 + c;
                    ev = (kabs <= qabs) ? ev : 0.f;
                }
                l_acc[r] += ev;
            }
        }
    }
    #pragma unroll
    for (int r = 0; r < 4; ++r) {
        l_acc[r] += __shfl_xor(l_acc[r], 1);
        l_acc[r] += __shfl_xor(l_acc[r], 2);
        l_acc[r] += __shfl_xor(l_acc[r], 4);
        l_acc[r] += __shfl_xor(l_acc[r], 8);
    }
    if (lm == 0) {
        #pragma unroll
        for (int r = 0; r < 4; ++r) {
            int row = w * 16 + hq * 4 + r;
            lpart[((size_t)qblock * 64 + row) * 4 + chunk] = l_acc[r];
        }
    }
}

// ---------------- importance B: column sums per (b,h,kt), XCD-chunked ----------------
// grid 2048 (2048%8==0, bijective); 256-bid chunks per XCD -> K tables L2-resident.
__global__ __launch_bounds__(256, 4)
void imp_col_kernel(const unsigned short* __restrict__ Qhp, const unsigned short* __restrict__ Qlp,
                    const unsigned short* __restrict__ Kbp, const unsigned short* __restrict__ Klop,
                    const float* __restrict__ lpart, float* __restrict__ imp)
{
    __shared__ __align__(16) unsigned short khi[64 * 128];
    __shared__ __align__(16) unsigned short klo[64 * 128];
    __shared__ float imp_loc[64];

    int bid = (blockIdx.x & 7) * 256 + (blockIdx.x >> 3);   // XCD chunking
    int kt = bid & 15;
    int h  = (bid >> 4) & 31;
    int b  = bid >> 9;
    int hkv = h >> 2;
    int t = threadIdx.x;
    int w = t >> 6;
    int l = t & 63;
    int lm = l & 15;
    int hq = l >> 4;

    if (t < 64) imp_loc[t] = 0.f;
    size_t tbase = (size_t)((b * HKV_ + hkv) * 16 + kt) * TILE_US;
    {
        const uintx4* hg = (const uintx4*)(Kbp + tbase) + t;
        const uintx4* lg = (const uintx4*)(Klop + tbase) + t;
        uintx4* hd = (uintx4*)khi + t;
        uintx4* ld = (uintx4*)klo + t;
        #pragma unroll
        for (int i = 0; i < 4; ++i) {
            hd[i * 256] = hg[i * 256];
            ld[i * 256] = lg[i * 256];
        }
    }
    __syncthreads();

    float cs[4] = {0.f, 0.f, 0.f, 0.f};
    for (int qp2 = 0; qp2 < 2; ++qp2) {
        if (kt == 15 && qp2 == 0) continue;
        int qbid = (b * 32 + h) * 2 + qp2;
        int q0 = 896 + qp2 * 64;
        short8 aqh[4], aql[4];
        #pragma unroll
        for (int c = 0; c < 4; ++c) {
            size_t idx = (((size_t)qbid * 4 + c) * 256 + t) * 8;
            aqh[c] = *(const short8*)&Qhp[idx];
            aql[c] = *(const short8*)&Qlp[idx];
        }
        floatx4 iv4;
        #pragma unroll
        for (int r = 0; r < 4; ++r) {
            int row = w * 16 + hq * 4 + r;
            float4 p = *(const float4*)&lpart[((size_t)qbid * 64 + row) * 4];
            iv4[r] = 1.0f / ((p.x + p.y) + (p.z + p.w));
        }

        floatx4 S[4];
        #pragma unroll
        for (int c = 0; c < 4; ++c) S[c] = (floatx4){-M_FIX, -M_FIX, -M_FIX, -M_FIX};
        #pragma unroll
        for (int kc = 0; kc < 4; ++kc) {
            #pragma unroll
            for (int c = 0; c < 4; ++c) {
                int row = lm * 4 + c;
                int phys = (kc * 4 + hq) ^ (row & 15);
                short8 bh = *(const short8*)&khi[row * 128 + phys * 8];
                short8 bl = *(const short8*)&klo[row * 128 + phys * 8];
                S[c] = __builtin_amdgcn_mfma_f32_16x16x32_bf16(aqh[kc], bh, S[c], 0, 0, 0);
                S[c] = __builtin_amdgcn_mfma_f32_16x16x32_bf16(aqh[kc], bl, S[c], 0, 0, 0);
                S[c] = __builtin_amdgcn_mfma_f32_16x16x32_bf16(aql[kc], bh, S[c], 0, 0, 0);
            }
        }
        #pragma unroll
        for (int c = 0; c < 4; ++c) {
            int kabs = kt * 64 + lm * 4 + c;
            #pragma unroll
            for (int r = 0; r < 4; ++r) {
                int qabs = q0 + w * 16 + hq * 4 + r;
                float ev = (kabs <= qabs) ? __expf(S[c][r]) : 0.f;
                cs[c] += ev * iv4[r];
            }
        }
    }
    #pragma unroll
    for (int c = 0; c < 4; ++c) {
        cs[c] += __shfl_xor(cs[c], 16);
        cs[c] += __shfl_xor(cs[c], 32);
    }
    if (l < 16) {
        #pragma unroll
        for (int c = 0; c < 4; ++c) atomicAdd(&imp_loc[lm * 4 + c], cs[c]);
    }
    __syncthreads();
    if (t < 64) atomicAdd(&imp[b * L_ + kt * 64 + t], imp_loc[t]);
}

// ---------------- top-k 512 of 1024 per batch; optionally emits inverse slot map ----------------
__global__ void topk_kernel(const float* __restrict__ imp, const int* __restrict__ slot_mapping,
                            int* __restrict__ keep, int* __restrict__ inv)
{
    __shared__ float vals[1024];
    __shared__ int   idxs[1024];
    int b = blockIdx.x;
    int t = threadIdx.x;   // 512 threads
    for (int i = t; i < 1024; i += 512) { vals[i] = imp[b * L_ + i]; idxs[i] = i; }

    for (int size = 2; size <= 1024; size <<= 1) {
        for (int stride = size >> 1; stride > 0; stride >>= 1) {
            __syncthreads();
            for (int i = t; i < 1024; i += 512) {
                int j = i ^ stride;
                if (j > i) {
                    float vi = vals[i], vj = vals[j];
                    int ii = idxs[i], ij = idxs[j];
                    bool j_before_i = (vj > vi) || (vj == vi && ij < ii);
                    bool descRegion = ((i & size) == 0);
                    bool doSwap = descRegion ? j_before_i : !j_before_i;
                    if (doSwap) {
                        vals[i] = vj; vals[j] = vi;
                        idxs[i] = ij; idxs[j] = ii;
                    }
                }
            }
        }
    }
    __syncthreads();
    for (int size = 2; size <= 512; size <<= 1) {
        for (int stride = size >> 1; stride > 0; stride >>= 1) {
            __syncthreads();
            int i = t, j = t ^ stride;
            if (j > i) {
                int a = idxs[i], bb = idxs[j];
                bool ascRegion = ((i & size) == 0);
                bool doSwap = ascRegion ? (a > bb) : (a < bb);
                if (doSwap) { idxs[i] = bb; idxs[j] = a; }
            }
        }
    }
    __syncthreads();
    keep[b * KEEP_ + t] = idxs[t];
    if (inv) {
        int dest = slot_mapping[b * L_ + t];        // j = t < 512
        inv[dest] = b * L_ + idxs[t];               // global source row
    }
}

// ---------------- fused cache output: every slot written exactly once ----------------
__global__ __launch_bounds__(256)
void cache_out_kernel(const float* __restrict__ kin, const float* __restrict__ vin,
                      const float* __restrict__ kc_in, const float* __restrict__ vc_in,
                      const int* __restrict__ inv,
                      float* __restrict__ kc_out, float* __restrict__ vc_out)
{
    int bid = blockIdx.x;
    int t = threadIdx.x;
    #pragma unroll
    for (int i = 0; i < 4; ++i) {
        int s = bid * 4 + i;
        int src = inv[s];
        const float4* kp = (src >= 0) ? (const float4*)&kin[(size_t)src * 1024]
                                      : (const float4*)&kc_in[(size_t)s * 1024];
        const float4* vp = (src >= 0) ? (const float4*)&vin[(size_t)src * 1024]
                                      : (const float4*)&vc_in[(size_t)s * 1024];
        ((float4*)&kc_out[(size_t)s * 1024])[t] = kp[t];
        ((float4*)&vc_out[(size_t)s * 1024])[t] = vp[t];
    }
}

// ---------------- fallback pair (used only if workspace too small for inv) ----------------
__global__ __launch_bounds__(256)
void cache_copy_kernel(const float* __restrict__ kc_in, const float* __restrict__ vc_in,
                       float* __restrict__ kc_out, float* __restrict__ vc_out)
{
    size_t idx = (size_t)blockIdx.x * 256 + threadIdx.x;
    const float4* ki = (const float4*)kc_in;
    const float4* vi = (const float4*)vc_in;
    float4* ko = (float4*)kc_out;
    float4* vo = (float4*)vc_out;
    #pragma unroll
    for (int i = 0; i < 4; ++i) {
        size_t off = idx + (size_t)i * 524288;
        ko[off] = ki[off];
        vo[off] = vi[off];
    }
}

__global__ void scatter_kernel(const float* __restrict__ kin, const float* __restrict__ vin,
                               const int* __restrict__ keep, const int* __restrict__ slot_mapping,
                               float* __restrict__ kc_out, float* __restrict__ vc_out)
{
    int bid = blockIdx.x;
    int b = bid >> 9, j = bid & 511;
    int src = b * L_ + keep[b * KEEP_ + j];
    int dst = slot_mapping[b * L_ + j];
    int t = threadIdx.x;
    float4 kv = *(const float4*)&kin[(size_t)src * 1024 + t * 4];
    *(float4*)&kc_out[(size_t)dst * 1024 + t * 4] = kv;
    float4 vv = *(const float4*)&vin[(size_t)src * 1024 + t * 4];
    *(float4*)&vc_out[(size_t)dst * 1024 + t * 4] = vv;
}

extern "C" void kernel_launch(void* const* d_in, const int* in_sizes, int n_in,
                              void* d_out, int out_size, void* d_ws, size_t ws_size,
                              hipStream_t stream)
{
    const float* q = (const float*)d_in[0];
    const float* k = (const float*)d_in[1];
    const float* v = (const float*)d_in[2];
    const float* k_cache = (const float*)d_in[3];
    const float* v_cache = (const float*)d_in[4];
    const int* slot_mapping = (const int*)d_in[5];

    float* o = (float*)d_out;
    float* kc_out = o + O_ELEMS;
    float* vc_out = kc_out + CACHE_ELEMS;

    // workspace: imp 16K | keep 8K | (unused 64K) | inv 32K  (120 KB)
    float* imp  = (float*)d_ws;                    // 4096 f
    int*   keep = (int*)(imp + B_ * L_);           // 2048 i
    float* invL = (float*)(keep + B_ * KEEP_);     // 16384 f (layout-compat spacer)
    int*   inv  = (int*)(invL + B_ * H_ * 128);    // 8192 i @ 88 KB
    bool use_inv = ws_size >= (size_t)(120 * 1024);
    if (!use_inv) inv = nullptr;

    // lpart (256 KB partial row-sums) lives in the kc_out output region, which is
    // untouched until cache-out time (after all lpart consumers).
    float* lpart = kc_out;

    // bf16 staging scratch (32 MB): Kb/Klo/VTb 8MB each + Qh/Ql 4MB each.
    const size_t SCRATCH_US = (size_t)3 * 512 * TILE_US + (size_t)2 * QTAB_US;
    bool ws_fits = ws_size >= (size_t)(128 * 1024) + SCRATCH_US * sizeof(unsigned short);
    unsigned short* Kb = ws_fits ? (unsigned short*)((char*)d_ws + 128 * 1024)
                                 : (unsigned short*)vc_out;
    unsigned short* Klo = Kb  + (size_t)512 * TILE_US;
    unsigned short* VTb = Klo + (size_t)512 * TILE_US;
    unsigned short* Qh  = VTb + (size_t)512 * TILE_US;
    unsigned short* Ql  = Qh  + (size_t)QTAB_US;

    (void)hipMemsetAsync(imp, 0, B_ * L_ * 4, stream);
    if (use_inv) (void)hipMemsetAsync(inv, 0xFF, 8192 * 4, stream);   // -1 sentinel

    convert_kernel<<<dim3(512), dim3(256), 0, stream>>>(k, v, q, Kb, Klo, VTb, Qh, Ql);
    attn_mfma<<<dim3(512), dim3(512), 0, stream>>>(q, Kb, VTb, o);
    imp_lsum_kernel<<<dim3(1024), dim3(256), 0, stream>>>(Qh, Ql, Kb, Klo, lpart);
    imp_col_kernel<<<dim3(2048), dim3(256), 0, stream>>>(Qh, Ql, Kb, Klo, lpart, imp);
    topk_kernel<<<dim3(4), dim3(512), 0, stream>>>(imp, slot_mapping, keep, inv);

    if (use_inv) {
        cache_out_kernel<<<dim3(2048), dim3(256), 0, stream>>>(k, v, k_cache, v_cache, inv, kc_out, vc_out);
    } else {
        cache_copy_kernel<<<dim3(2048), dim3(256), 0, stream>>>(k_cache, v_cache, kc_out, vc_out);
        scatter_kernel<<<dim3(2048), dim3(256), 0, stream>>>(k, v, keep, slot_mapping, kc_out, vc_out);
    }
}